// Round 3
// baseline (1581.610 us; speedup 1.0000x reference)
//
#include <hip/hip_runtime.h>
#include <cstdint>
#include <cstddef>

#define P_TOT 114688   // N*H*W = 4*128*224
#define W_IMG 224
#define H_IMG 128

typedef _Float16 f16;
typedef __attribute__((ext_vector_type(8))) _Float16 f16x8;
typedef __attribute__((ext_vector_type(4))) _Float16 f16x4;
typedef __attribute__((ext_vector_type(2))) _Float16 f16x2;
typedef __attribute__((ext_vector_type(4))) float f32x4;

#define WAITVM(N) asm volatile("s_waitcnt vmcnt(" #N ")" ::: "memory")

__device__ __forceinline__ void barrier_sync() {
  asm volatile("" ::: "memory");
  __builtin_amdgcn_s_barrier();
  asm volatile("" ::: "memory");
}

__device__ __forceinline__ void gload16(const void* g, void* l) {
  __builtin_amdgcn_global_load_lds((const __attribute__((address_space(1))) void*)g,
                                   (__attribute__((address_space(3))) void*)l, 16, 0, 0);
}

// ---------------- pack input: fp32 NCHW -> fp16 NHWC, chunk-swizzled -------------
// stored slot = true_chunk ^ ((w>>1)&3)  within each 32-ch group (rows pair on bank parity)
__global__ void k_pack_x(const float* __restrict__ x, f16* __restrict__ xb) {
  int gid = blockIdx.x * 256 + threadIdx.x;           // total P_TOT*32
  if (gid >= P_TOT * 32) return;
  int c8 = gid & 31;
  int p  = gid >> 5;
  int w  = p % W_IMG;
  int h  = (p / W_IMG) % H_IMG;
  int n  = p / (H_IMG * W_IMG);
  const float* src = x + ((size_t)(n * 256 + c8 * 8) * H_IMG + h) * W_IMG + w;
  f16x8 v;
#pragma unroll
  for (int j = 0; j < 8; j++) v[j] = (f16)src[(size_t)j * (H_IMG * W_IMG)];
  int c8s = (c8 & ~3) | ((c8 ^ (w >> 1)) & 3);
  *(f16x8*)(xb + (size_t)p * 256 + c8s * 8) = v;
}

// ---------------- pack weights into [kk][CS/32][OT][32], swizzled by ((o>>1)&3) --
__global__ void k_pack_w(const float* __restrict__ wa, const float* __restrict__ wb,
                         f16* __restrict__ dst, int mode, int OT, int CS,
                         int Coh, int Cih, int total) {
  int gid = blockIdx.x * 256 + threadIdx.x;
  if (gid >= total) return;
  int j  = gid & 31;
  int t1 = gid >> 5;
  int o  = t1 % OT;
  int t2 = t1 / OT;
  int CCc = CS >> 5;
  int cc = t2 % CCc;
  int kk = t2 / CCc;
  int chunkT = ((j >> 3) ^ (o >> 1)) & 3;   // stored slot holds true chunk slot^key
  int is = cc * 32 + chunkT * 8 + (j & 7);
  float val = 0.f;
  if (mode == 0) {
    val = (o < Coh) ? wa[((size_t)o * Cih + is) * 9 + kk]
                    : wb[((size_t)(o - Coh) * Cih + is) * 9 + kk];
  } else if (mode == 1) {
    if (o < Coh) {
      val = (is < Cih) ? wa[((size_t)o * Cih + is) * 9 + kk]
                       : -wb[((size_t)o * Cih + (is - Cih)) * 9 + kk];
    } else {
      int oo = o - Coh;
      val = (is < Cih) ? wb[((size_t)oo * Cih + is) * 9 + kk]
                       : wa[((size_t)oo * Cih + (is - Cih)) * 9 + kk];
    }
  } else {
    if (o == 0)      val = wa[(size_t)is * 9 + kk];
    else if (o == 1) val = wb[(size_t)is * 9 + kk];
    else if (o == 2) val = wb[(size_t)(96 + is) * 9 + kk];
  }
  dst[gid] = (f16)val;
}

// ---------------- implicit-GEMM conv, MFMA fp16, 2-buffer + counted vmcnt -------
template<int BM, int OT, int CS, int WM, int WN, bool HEAD>
__launch_bounds__(WM * WN * 64, HEAD ? 1 : 4)
__global__ void k_gemm(const f16* __restrict__ xb, const f16* __restrict__ Apack,
                       const char* __restrict__ zerop,
                       f16* __restrict__ y, float* __restrict__ outh,
                       const float* __restrict__ bcp, const float* __restrict__ bgp,
                       float* __restrict__ sums, float* __restrict__ sumsq) {
  constexpr int NT = WM * WN * 64;
  constexpr int NWV = NT / 64;
  constexpr int CC = CS / 32;
  constexpr int MF = BM / (WM * 16);
  constexpr int NF = 224 / (WN * 16);
  constexpr int STEPS = 9 * CC;
  constexpr int TILE = (BM + 224) * 32;   // f16 per buffer (A then B)
  constexpr int ACH = BM / 16;            // A 1KB-chunks
  constexpr int TCH = ACH + 14;           // total 1KB-chunks per stage
  static_assert(HEAD || (TCH % NWV == 0 && TCH / NWV == 5), "vmcnt math assumes 5 loads/thread");
  __shared__ f16 lds[2][TILE];

  constexpr int NOT = OT / BM;
  constexpr int nwg = NOT * 512;
  int bid = blockIdx.x;
  int swz = (bid & 7) * (nwg >> 3) + (bid >> 3);  // XCD swizzle (nwg % 8 == 0)
  const int ot = swz % NOT;                        // ot fastest -> same-B blocks adjacent
  const int rq = swz / NOT;
  const int n = rq >> 7;
  const int h = rq & 127;
  const int tid  = threadIdx.x;
  const int lane = tid & 63;
  const int wv   = tid >> 6;
  const int wm   = wv % WM;
  const int wn   = wv / WM;
  const int obase  = wm * (MF * 16);
  const int wnbase = wn * (NF * 16);
  const int l15 = lane & 15;
  const int lhi = lane >> 4;
  // A frag: row = obase+mi*16+l15 (stride 64B); slot = lhi ^ ((row>>1)&3) -> 2-way max
  const int aoff = l15 * 64 + (((lhi ^ (l15 >> 1)) & 3) << 4);

  f32x4 acc[MF][NF];
#pragma unroll
  for (int mi = 0; mi < MF; mi++)
#pragma unroll
    for (int ni = 0; ni < NF; ni++) acc[mi][ni] = (f32x4){0.f, 0.f, 0.f, 0.f};

  const size_t rowstride = (size_t)CS * 2;   // bytes per pixel in xb

  auto stage = [&](int buf, int kk, int c) {
    const char* asrc = (const char*)(Apack + ((size_t)(kk * CC + c) * OT + ot * BM) * 32);
    const int dh = kk / 3 - 1;
    const int dw = kk % 3 - 1;
    const int hp = h + dh;
    const bool hok = (hp >= 0) && (hp < H_IMG);
    const int hpc = hok ? hp : 0;
    const char* brow = (const char*)xb + ((size_t)(n * H_IMG + hpc) * W_IMG) * rowstride + c * 64;
    char* base = (char*)&lds[buf][0];
#pragma unroll
    for (int ck = wv; ck < TCH; ck += NWV) {
      char* dst = base + ck * 1024;           // wave-uniform
      if (ck < ACH) {
        gload16(asrc + ck * 1024 + lane * 16, dst);
      } else {
        int bidx = ck - ACH;
        int px = bidx * 16 + (lane >> 2);
        int ch = lane & 3;
        int wp = px + dw;
        bool ok = hok && ((unsigned)wp < 224u);
        const char* src = ok ? brow + (size_t)wp * rowstride + ch * 16
                             : zerop + ch * 16;
        gload16(src, dst);
      }
    }
  };

  auto compute = [&](int buf, int kk) {
    const int dw = kk % 3 - 1;
    const char* Ab = (const char*)&lds[buf][0];
    const char* Bb = (const char*)&lds[buf][BM * 32];
    f16x8 af[MF], bfr[NF];
#pragma unroll
    for (int mi = 0; mi < MF; mi++)
      af[mi] = *(const f16x8*)(Ab + (obase + mi * 16) * 64 + aoff);
#pragma unroll
    for (int ni = 0; ni < NF; ni++) {
      int px = wnbase + ni * 16 + l15;
      int rowb = px * 64;
      // stored key for global pixel wp=px+dw is ((wp>>1)&3); slot = lhi ^ key
      int sw = ((lhi ^ ((px + dw) >> 1)) & 3) << 4;
      bfr[ni] = *(const f16x8*)(Bb + rowb + sw);
    }
#pragma unroll
    for (int mi = 0; mi < MF; mi++)
#pragma unroll
      for (int ni = 0; ni < NF; ni++)
        acc[mi][ni] = __builtin_amdgcn_mfma_f32_16x16x32_f16(af[mi], bfr[ni], acc[mi][ni], 0, 0, 0);
  };

  if constexpr (!HEAD) {
    // 2-buffer, counted vmcnt: stage(t+1) issued before waiting on stage(t)
    stage(0, 0, 0);
    for (int t = 0; t < STEPS; ++t) {
      int tn = t + 1;
      if (tn < STEPS) { stage(tn & 1, tn / CC, tn % CC); WAITVM(5); }
      else            { WAITVM(0); }
      barrier_sync();
      compute(t & 1, t / CC);
      barrier_sync();
    }
  } else {
    stage(0, 0, 0);
    __syncthreads();
    int buf = 0;
    for (int t = 0; t < STEPS; ++t) {
      int tn = t + 1;
      if (tn < STEPS) stage(buf ^ 1, tn / CC, tn % CC);
      compute(buf, t / CC);
      __syncthreads();
      buf ^= 1;
    }
  }

  const size_t prow = (size_t)(n * H_IMG + h) * W_IMG;
  if constexpr (!HEAD) {
    // store fp16 NHWC output
#pragma unroll
    for (int mi = 0; mi < MF; mi++) {
#pragma unroll
      for (int ni = 0; ni < NF; ni++) {
        int o = obase + mi * 16 + lhi * 4;
        int w = wnbase + ni * 16 + l15;
        f16x4 v4;
#pragma unroll
        for (int j = 0; j < 4; j++) v4[j] = (f16)acc[mi][ni][j];
        *(f16x4*)(y + (prow + w) * OT + ot * BM + o) = v4;
      }
    }
    // fused BN stats: per-channel sum / sumsq partials
    float sv[MF][4], qv[MF][4];
#pragma unroll
    for (int mi = 0; mi < MF; mi++)
#pragma unroll
      for (int j = 0; j < 4; j++) {
        float s = 0.f, q = 0.f;
#pragma unroll
        for (int ni = 0; ni < NF; ni++) {
          float v = acc[mi][ni][j];
          s += v; q += v * v;
        }
        sv[mi][j] = s; qv[mi][j] = q;
      }
#pragma unroll
    for (int m = 1; m < 16; m <<= 1) {
#pragma unroll
      for (int mi = 0; mi < MF; mi++)
#pragma unroll
        for (int j = 0; j < 4; j++) {
          sv[mi][j] += __shfl_xor(sv[mi][j], m);
          qv[mi][j] += __shfl_xor(qv[mi][j], m);
        }
    }
    if (l15 == 0) {
#pragma unroll
      for (int mi = 0; mi < MF; mi++)
#pragma unroll
        for (int j = 0; j < 4; j++) {
          int ch = ot * BM + obase + mi * 16 + lhi * 4 + j;
          atomicAdd(&sums[ch], sv[mi][j]);
          atomicAdd(&sumsq[ch], qv[mi][j]);
        }
    }
  } else {
    if (lhi == 0) {
      float b0 = bcp[0], b1 = bgp[0], b2 = bgp[1];
#pragma unroll
      for (int ni = 0; ni < NF; ni++) {
        int w = wnbase + ni * 16 + l15;
        float c0 = acc[0][ni][0] + b0;
        c0 = 1.f / (1.f + expf(-c0));
        float c1 = acc[0][ni][1] + b1;
        float c2 = acc[0][ni][2] + b2;
        outh[((size_t)(n * 3 + 0) * H_IMG + h) * W_IMG + w] = c0;
        outh[((size_t)(n * 3 + 1) * H_IMG + h) * W_IMG + w] = c1;
        outh[((size_t)(n * 3 + 2) * H_IMG + h) * W_IMG + w] = c2;
      }
    }
  }
}

__global__ void k_finalize(const float* __restrict__ sums, const float* __restrict__ sumsq,
                           const float* __restrict__ g, const float* __restrict__ b,
                           float* __restrict__ scale, float* __restrict__ shift,
                           int O, int Half) {
  int t = threadIdx.x;
  if (t >= O) return;
  const float inv = 1.0f / (float)P_TOT;
  float mean = sums[t] * inv;
  float var  = fmaxf(sumsq[t] * inv - mean * mean, 0.f);
  int gi = (t < Half) ? t : (t - Half);
  float sc = g[gi] * rsqrtf(var + 1e-5f);
  scale[t] = sc;
  shift[t] = b[gi] - mean * sc;
}

// ---------------- in-place BN + ReLU + chunk-swizzle ----------------------------
template<int O>
__global__ void k_packip(f16* __restrict__ y, const float* __restrict__ scale,
                         const float* __restrict__ shift) {
  constexpr int G32 = O / 32;
  int gid = blockIdx.x * 256 + threadIdx.x;
  if (gid >= P_TOT * G32) return;
  int g = gid % G32;
  int p = gid / G32;
  int w = p % W_IMG;
  f16* base = y + (size_t)p * O + g * 32;
  f16x8 in[4];
#pragma unroll
  for (int ch = 0; ch < 4; ch++) in[ch] = *(const f16x8*)(base + ch * 8);
  int sw = (w >> 1) & 3;
  f16x8 outv[4];
#pragma unroll
  for (int ch = 0; ch < 4; ch++) {
#pragma unroll
    for (int j = 0; j < 8; j++) {
      int cdx = g * 32 + ch * 8 + j;
      float f = fmaxf(fmaf((float)in[ch][j], scale[cdx], shift[cdx]), 0.f);
      outv[ch][j] = (f16)f;
    }
  }
#pragma unroll
  for (int ch = 0; ch < 4; ch++) *(f16x8*)(base + ((ch ^ sw) & 3) * 8) = outv[ch];
}

// ---------------- BN(L4) + ReLU + complex magnitude -> 96ch swizzled ------------
__global__ void k_mag(const f16* __restrict__ y, const float* __restrict__ scale,
                      const float* __restrict__ shift, f16* __restrict__ mg) {
  int gid = blockIdx.x * 256 + threadIdx.x;
  if (gid >= P_TOT * 12) return;
  int c8 = gid % 12;
  int p  = gid / 12;
  int w  = p % W_IMG;
  f16x8 r8 = *(const f16x8*)(y + (size_t)p * 192 + c8 * 8);
  f16x8 i8 = *(const f16x8*)(y + (size_t)p * 192 + 96 + c8 * 8);
  f16x8 outv;
#pragma unroll
  for (int j = 0; j < 8; j++) {
    int cdx = c8 * 8 + j;
    float rr = fmaxf(fmaf((float)r8[j], scale[cdx], shift[cdx]), 0.f);
    float ii = fmaxf(fmaf((float)i8[j], scale[96 + cdx], shift[96 + cdx]), 0.f);
    outv[j] = (f16)sqrtf(rr * rr + ii * ii);
  }
  int c8s = (c8 & ~3) | ((c8 ^ (w >> 1)) & 3);
  *(f16x8*)(mg + (size_t)p * 96 + c8s * 8) = outv;
}

// ------------------------------------------------------------------------------
extern "C" void kernel_launch(void* const* d_in, const int* in_sizes, int n_in,
                              void* d_out, int out_size, void* d_ws, size_t ws_size,
                              hipStream_t stream) {
  const float* x   = (const float*)d_in[0];
  const float* w1r = (const float*)d_in[1];
  const float* w1i = (const float*)d_in[2];
  const float* g1  = (const float*)d_in[3];
  const float* b1  = (const float*)d_in[4];
  const float* w2r = (const float*)d_in[5];
  const float* w2i = (const float*)d_in[6];
  const float* g2  = (const float*)d_in[7];
  const float* b2  = (const float*)d_in[8];
  const float* w3r = (const float*)d_in[9];
  const float* w3i = (const float*)d_in[10];
  const float* g3  = (const float*)d_in[11];
  const float* b3  = (const float*)d_in[12];
  const float* w4r = (const float*)d_in[13];
  const float* w4i = (const float*)d_in[14];
  const float* g4  = (const float*)d_in[15];
  const float* b4  = (const float*)d_in[16];
  const float* wc  = (const float*)d_in[17];
  const float* bcp = (const float*)d_in[18];
  const float* wg  = (const float*)d_in[19];
  const float* bgp = (const float*)d_in[20];
  float* out = (float*)d_out;

  char* ws = (char*)d_ws;
  if (ws_size < 137500000ULL) return;

  char* zerop = ws;                              // 16KB zero page
  auto S  = [&](int L) { return (float*)(ws + 16384 + L * 4096); };
  auto Q  = [&](int L) { return (float*)(ws + 16384 + L * 4096) + 512; };
  auto SC = [&](int L) { return (float*)(ws + 32768 + L * 4096); };
  auto SH = [&](int L) { return (float*)(ws + 32768 + L * 4096) + 512; };
  f16* A1 = (f16*)(ws + 65536);
  f16* A2 = (f16*)(ws + 1392640);
  f16* A3 = (f16*)(ws + 2387968);
  f16* A4 = (f16*)(ws + 3051520);
  f16* AH = (f16*)(ws + 3715072);
  f16* XB0 = (f16*)(ws + (8ULL << 20));
  f16* Y   = (f16*)(ws + (68ULL << 20));

  hipMemsetAsync(d_ws, 0, 49152, stream);  // zero page + stats sums

  k_pack_x<<<P_TOT * 32 / 256, 256, 0, stream>>>(x, XB0);
  k_pack_w<<<(663552 + 255) / 256, 256, 0, stream>>>(w1r, w1i, A1, 0, 288, 256, 144, 256, 663552);
  k_pack_w<<<(497664 + 255) / 256, 256, 0, stream>>>(w2r, w2i, A2, 1, 192, 288, 96, 144, 497664);
  k_pack_w<<<(331776 + 255) / 256, 256, 0, stream>>>(w3r, w3i, A3, 1, 192, 192, 96, 96, 331776);
  k_pack_w<<<(331776 + 255) / 256, 256, 0, stream>>>(w4r, w4i, A4, 1, 192, 192, 96, 96, 331776);
  k_pack_w<<<(13824 + 255) / 256, 256, 0, stream>>>(wc, wg, AH, 2, 16, 96, 0, 96, 13824);

  // L1: 256 -> 288
  k_gemm<96, 288, 256, 2, 2, false><<<1536, 256, 0, stream>>>(XB0, A1, zerop, Y, nullptr, nullptr, nullptr, S(0), Q(0));
  k_finalize<<<1, 512, 0, stream>>>(S(0), Q(0), g1, b1, SC(0), SH(0), 288, 144);
  k_packip<288><<<P_TOT * 9 / 256, 256, 0, stream>>>(Y, SC(0), SH(0));

  // L2: 288 -> 192
  k_gemm<96, 192, 288, 2, 2, false><<<1024, 256, 0, stream>>>(Y, A2, zerop, XB0, nullptr, nullptr, nullptr, S(1), Q(1));
  k_finalize<<<1, 512, 0, stream>>>(S(1), Q(1), g2, b2, SC(1), SH(1), 192, 96);
  k_packip<192><<<P_TOT * 6 / 256, 256, 0, stream>>>(XB0, SC(1), SH(1));

  // L3: 192 -> 192
  k_gemm<96, 192, 192, 2, 2, false><<<1024, 256, 0, stream>>>(XB0, A3, zerop, Y, nullptr, nullptr, nullptr, S(2), Q(2));
  k_finalize<<<1, 512, 0, stream>>>(S(2), Q(2), g3, b3, SC(2), SH(2), 192, 96);
  k_packip<192><<<P_TOT * 6 / 256, 256, 0, stream>>>(Y, SC(2), SH(2));

  // L4: 192 -> 192
  k_gemm<96, 192, 192, 2, 2, false><<<1024, 256, 0, stream>>>(Y, A4, zerop, XB0, nullptr, nullptr, nullptr, S(3), Q(3));
  k_finalize<<<1, 512, 0, stream>>>(S(3), Q(3), g4, b4, SC(3), SH(3), 192, 96);

  // BN+ReLU+magnitude -> 96ch head input
  k_mag<<<P_TOT * 12 / 256, 256, 0, stream>>>(XB0, SC(3), SH(3), Y);

  // head: 96 -> 3 (sigmoid on ch0), writes NCHW fp32 output
  k_gemm<16, 16, 96, 1, 2, true><<<512, 128, 0, stream>>>(Y, AH, zerop, nullptr, out, bcp, bgp, nullptr, nullptr);

  (void)in_sizes; (void)n_in; (void)out_size;
}

// Round 4
// 1009.194 us; speedup vs baseline: 1.5672x; 1.5672x over previous
//
#include <hip/hip_runtime.h>
#include <cstdint>
#include <cstddef>

#define P_TOT 114688   // N*H*W = 4*128*224
#define W_IMG 224
#define H_IMG 128

typedef _Float16 f16;
typedef __attribute__((ext_vector_type(8))) _Float16 f16x8;
typedef __attribute__((ext_vector_type(4))) _Float16 f16x4;
typedef __attribute__((ext_vector_type(2))) _Float16 f16x2;
typedef __attribute__((ext_vector_type(4))) float f32x4;

#define WAITVM(N) asm volatile("s_waitcnt vmcnt(" #N ")" ::: "memory")

__device__ __forceinline__ void barrier_sync() {
  asm volatile("" ::: "memory");
  __builtin_amdgcn_s_barrier();
  asm volatile("" ::: "memory");
}

__device__ __forceinline__ void gload16(const void* g, void* l) {
  __builtin_amdgcn_global_load_lds((const __attribute__((address_space(1))) void*)g,
                                   (__attribute__((address_space(3))) void*)l, 16, 0, 0);
}

// ---------------- pack input: fp32 NCHW -> fp16 NHWC, chunk-swizzled -------------
// stored slot = true_chunk ^ ((w>>1)&3)  within each 32-ch group (rows pair on bank parity)
__global__ void k_pack_x(const float* __restrict__ x, f16* __restrict__ xb) {
  int gid = blockIdx.x * 256 + threadIdx.x;           // total P_TOT*32
  if (gid >= P_TOT * 32) return;
  int c8 = gid & 31;
  int p  = gid >> 5;
  int w  = p % W_IMG;
  int h  = (p / W_IMG) % H_IMG;
  int n  = p / (H_IMG * W_IMG);
  const float* src = x + ((size_t)(n * 256 + c8 * 8) * H_IMG + h) * W_IMG + w;
  f16x8 v;
#pragma unroll
  for (int j = 0; j < 8; j++) v[j] = (f16)src[(size_t)j * (H_IMG * W_IMG)];
  int c8s = (c8 & ~3) | ((c8 ^ (w >> 1)) & 3);
  *(f16x8*)(xb + (size_t)p * 256 + c8s * 8) = v;
}

// ---------------- pack weights into [kk][CS/32][OT][32], swizzled by ((o>>1)&3) --
__global__ void k_pack_w(const float* __restrict__ wa, const float* __restrict__ wb,
                         f16* __restrict__ dst, int mode, int OT, int CS,
                         int Coh, int Cih, int total) {
  int gid = blockIdx.x * 256 + threadIdx.x;
  if (gid >= total) return;
  int j  = gid & 31;
  int t1 = gid >> 5;
  int o  = t1 % OT;
  int t2 = t1 / OT;
  int CCc = CS >> 5;
  int cc = t2 % CCc;
  int kk = t2 / CCc;
  int chunkT = ((j >> 3) ^ (o >> 1)) & 3;   // stored slot holds true chunk slot^key
  int is = cc * 32 + chunkT * 8 + (j & 7);
  float val = 0.f;
  if (mode == 0) {
    val = (o < Coh) ? wa[((size_t)o * Cih + is) * 9 + kk]
                    : wb[((size_t)(o - Coh) * Cih + is) * 9 + kk];
  } else if (mode == 1) {
    if (o < Coh) {
      val = (is < Cih) ? wa[((size_t)o * Cih + is) * 9 + kk]
                       : -wb[((size_t)o * Cih + (is - Cih)) * 9 + kk];
    } else {
      int oo = o - Coh;
      val = (is < Cih) ? wb[((size_t)oo * Cih + is) * 9 + kk]
                       : wa[((size_t)oo * Cih + (is - Cih)) * 9 + kk];
    }
  } else {
    if (o == 0)      val = wa[(size_t)is * 9 + kk];
    else if (o == 1) val = wb[(size_t)is * 9 + kk];
    else if (o == 2) val = wb[(size_t)(96 + is) * 9 + kk];
  }
  dst[gid] = (f16)val;
}

// ---------------- implicit-GEMM conv, MFMA fp16, 2-buffer + counted vmcnt -------
template<int BM, int OT, int CS, int WM, int WN, bool HEAD>
__launch_bounds__(WM * WN * 64)
__global__ void k_gemm(const f16* __restrict__ xb, const f16* __restrict__ Apack,
                       const char* __restrict__ zerop,
                       f16* __restrict__ y, float* __restrict__ outh,
                       const float* __restrict__ bcp, const float* __restrict__ bgp,
                       float* __restrict__ sums, float* __restrict__ sumsq) {
  constexpr int NT = WM * WN * 64;
  constexpr int NWV = NT / 64;
  constexpr int CC = CS / 32;
  constexpr int MF = BM / (WM * 16);
  constexpr int NF = 224 / (WN * 16);
  constexpr int STEPS = 9 * CC;
  constexpr int TILE = (BM + 224) * 32;   // f16 per buffer (A then B)
  constexpr int ACH = BM / 16;            // A 1KB-chunks
  constexpr int TCH = ACH + 14;           // total 1KB-chunks per stage
  static_assert(HEAD || (TCH % NWV == 0 && TCH / NWV == 5), "vmcnt math assumes 5 loads/thread");
  __shared__ f16 lds[2][TILE];

  constexpr int NOT = OT / BM;
  constexpr int nwg = NOT * 512;
  int bid = blockIdx.x;
  int swz = (bid & 7) * (nwg >> 3) + (bid >> 3);  // XCD swizzle (nwg % 8 == 0)
  const int ot = swz % NOT;                        // ot fastest -> same-B blocks adjacent
  const int rq = swz / NOT;
  const int n = rq >> 7;
  const int h = rq & 127;
  const int tid  = threadIdx.x;
  const int lane = tid & 63;
  const int wv   = tid >> 6;
  const int wm   = wv % WM;
  const int wn   = wv / WM;
  const int obase  = wm * (MF * 16);
  const int wnbase = wn * (NF * 16);
  const int l15 = lane & 15;
  const int lhi = lane >> 4;
  // A frag: row = obase+mi*16+l15 (stride 64B); slot = lhi ^ ((row>>1)&3) -> 2-way max
  const int aoff = l15 * 64 + (((lhi ^ (l15 >> 1)) & 3) << 4);

  f32x4 acc[MF][NF];
#pragma unroll
  for (int mi = 0; mi < MF; mi++)
#pragma unroll
    for (int ni = 0; ni < NF; ni++) acc[mi][ni] = (f32x4){0.f, 0.f, 0.f, 0.f};

  const size_t rowstride = (size_t)CS * 2;   // bytes per pixel in xb

  auto stage = [&](int buf, int kk, int c) {
    const char* asrc = (const char*)(Apack + ((size_t)(kk * CC + c) * OT + ot * BM) * 32);
    const int dh = kk / 3 - 1;
    const int dw = kk % 3 - 1;
    const int hp = h + dh;
    const bool hok = (hp >= 0) && (hp < H_IMG);
    const int hpc = hok ? hp : 0;
    const char* brow = (const char*)xb + ((size_t)(n * H_IMG + hpc) * W_IMG) * rowstride + c * 64;
    char* base = (char*)&lds[buf][0];
#pragma unroll
    for (int ck = wv; ck < TCH; ck += NWV) {
      char* dst = base + ck * 1024;           // wave-uniform
      if (ck < ACH) {
        gload16(asrc + ck * 1024 + lane * 16, dst);
      } else {
        int bidx = ck - ACH;
        int px = bidx * 16 + (lane >> 2);
        int ch = lane & 3;
        int wp = px + dw;
        bool ok = hok && ((unsigned)wp < 224u);
        const char* src = ok ? brow + (size_t)wp * rowstride + ch * 16
                             : zerop + ch * 16;
        gload16(src, dst);
      }
    }
  };

  auto compute = [&](int buf, int kk) {
    const int dw = kk % 3 - 1;
    const char* Ab = (const char*)&lds[buf][0];
    const char* Bb = (const char*)&lds[buf][BM * 32];
    f16x8 af[MF], bfr[NF];
#pragma unroll
    for (int mi = 0; mi < MF; mi++)
      af[mi] = *(const f16x8*)(Ab + (obase + mi * 16) * 64 + aoff);
#pragma unroll
    for (int ni = 0; ni < NF; ni++) {
      int px = wnbase + ni * 16 + l15;
      int rowb = px * 64;
      // stored key for global pixel wp=px+dw is ((wp>>1)&3); slot = lhi ^ key
      int sw = ((lhi ^ ((px + dw) >> 1)) & 3) << 4;
      bfr[ni] = *(const f16x8*)(Bb + rowb + sw);
    }
#pragma unroll
    for (int mi = 0; mi < MF; mi++)
#pragma unroll
      for (int ni = 0; ni < NF; ni++)
        acc[mi][ni] = __builtin_amdgcn_mfma_f32_16x16x32_f16(af[mi], bfr[ni], acc[mi][ni], 0, 0, 0);
  };

  if constexpr (!HEAD) {
    // 2-buffer, counted vmcnt: stage(t+1) issued before waiting on stage(t)
    stage(0, 0, 0);
    for (int t = 0; t < STEPS; ++t) {
      int tn = t + 1;
      if (tn < STEPS) { stage(tn & 1, tn / CC, tn % CC); WAITVM(5); }
      else            { WAITVM(0); }
      barrier_sync();
      compute(t & 1, t / CC);
      barrier_sync();
    }
  } else {
    stage(0, 0, 0);
    __syncthreads();
    int buf = 0;
    for (int t = 0; t < STEPS; ++t) {
      int tn = t + 1;
      if (tn < STEPS) stage(buf ^ 1, tn / CC, tn % CC);
      compute(buf, t / CC);
      __syncthreads();
      buf ^= 1;
    }
  }

  const size_t prow = (size_t)(n * H_IMG + h) * W_IMG;
  if constexpr (!HEAD) {
    // store fp16 NHWC output
#pragma unroll
    for (int mi = 0; mi < MF; mi++) {
#pragma unroll
      for (int ni = 0; ni < NF; ni++) {
        int o = obase + mi * 16 + lhi * 4;
        int w = wnbase + ni * 16 + l15;
        f16x4 v4;
#pragma unroll
        for (int j = 0; j < 4; j++) v4[j] = (f16)acc[mi][ni][j];
        *(f16x4*)(y + (prow + w) * OT + ot * BM + o) = v4;
      }
    }
    // fused BN stats: per-channel sum / sumsq partials
    float sv[MF][4], qv[MF][4];
#pragma unroll
    for (int mi = 0; mi < MF; mi++)
#pragma unroll
      for (int j = 0; j < 4; j++) {
        float s = 0.f, q = 0.f;
#pragma unroll
        for (int ni = 0; ni < NF; ni++) {
          float v = acc[mi][ni][j];
          s += v; q += v * v;
        }
        sv[mi][j] = s; qv[mi][j] = q;
      }
#pragma unroll
    for (int m = 1; m < 16; m <<= 1) {
#pragma unroll
      for (int mi = 0; mi < MF; mi++)
#pragma unroll
        for (int j = 0; j < 4; j++) {
          sv[mi][j] += __shfl_xor(sv[mi][j], m);
          qv[mi][j] += __shfl_xor(qv[mi][j], m);
        }
    }
    if (l15 == 0) {
#pragma unroll
      for (int mi = 0; mi < MF; mi++)
#pragma unroll
        for (int j = 0; j < 4; j++) {
          int ch = ot * BM + obase + mi * 16 + lhi * 4 + j;
          atomicAdd(&sums[ch], sv[mi][j]);
          atomicAdd(&sumsq[ch], qv[mi][j]);
        }
    }
  } else {
    if (lhi == 0) {
      float b0 = bcp[0], b1 = bgp[0], b2 = bgp[1];
#pragma unroll
      for (int ni = 0; ni < NF; ni++) {
        int w = wnbase + ni * 16 + l15;
        float c0 = acc[0][ni][0] + b0;
        c0 = 1.f / (1.f + expf(-c0));
        float c1 = acc[0][ni][1] + b1;
        float c2 = acc[0][ni][2] + b2;
        outh[((size_t)(n * 3 + 0) * H_IMG + h) * W_IMG + w] = c0;
        outh[((size_t)(n * 3 + 1) * H_IMG + h) * W_IMG + w] = c1;
        outh[((size_t)(n * 3 + 2) * H_IMG + h) * W_IMG + w] = c2;
      }
    }
  }
}

__global__ void k_finalize(const float* __restrict__ sums, const float* __restrict__ sumsq,
                           const float* __restrict__ g, const float* __restrict__ b,
                           float* __restrict__ scale, float* __restrict__ shift,
                           int O, int Half) {
  int t = threadIdx.x;
  if (t >= O) return;
  const float inv = 1.0f / (float)P_TOT;
  float mean = sums[t] * inv;
  float var  = fmaxf(sumsq[t] * inv - mean * mean, 0.f);
  int gi = (t < Half) ? t : (t - Half);
  float sc = g[gi] * rsqrtf(var + 1e-5f);
  scale[t] = sc;
  shift[t] = b[gi] - mean * sc;
}

// ---------------- in-place BN + ReLU + chunk-swizzle ----------------------------
template<int O>
__global__ void k_packip(f16* __restrict__ y, const float* __restrict__ scale,
                         const float* __restrict__ shift) {
  constexpr int G32 = O / 32;
  int gid = blockIdx.x * 256 + threadIdx.x;
  if (gid >= P_TOT * G32) return;
  int g = gid % G32;
  int p = gid / G32;
  int w = p % W_IMG;
  f16* base = y + (size_t)p * O + g * 32;
  f16x8 in[4];
#pragma unroll
  for (int ch = 0; ch < 4; ch++) in[ch] = *(const f16x8*)(base + ch * 8);
  int sw = (w >> 1) & 3;
  f16x8 outv[4];
#pragma unroll
  for (int ch = 0; ch < 4; ch++) {
#pragma unroll
    for (int j = 0; j < 8; j++) {
      int cdx = g * 32 + ch * 8 + j;
      float f = fmaxf(fmaf((float)in[ch][j], scale[cdx], shift[cdx]), 0.f);
      outv[ch][j] = (f16)f;
    }
  }
#pragma unroll
  for (int ch = 0; ch < 4; ch++) *(f16x8*)(base + ((ch ^ sw) & 3) * 8) = outv[ch];
}

// ---------------- BN(L4) + ReLU + complex magnitude -> 96ch swizzled ------------
__global__ void k_mag(const f16* __restrict__ y, const float* __restrict__ scale,
                      const float* __restrict__ shift, f16* __restrict__ mg) {
  int gid = blockIdx.x * 256 + threadIdx.x;
  if (gid >= P_TOT * 12) return;
  int c8 = gid % 12;
  int p  = gid / 12;
  int w  = p % W_IMG;
  f16x8 r8 = *(const f16x8*)(y + (size_t)p * 192 + c8 * 8);
  f16x8 i8 = *(const f16x8*)(y + (size_t)p * 192 + 96 + c8 * 8);
  f16x8 outv;
#pragma unroll
  for (int j = 0; j < 8; j++) {
    int cdx = c8 * 8 + j;
    float rr = fmaxf(fmaf((float)r8[j], scale[cdx], shift[cdx]), 0.f);
    float ii = fmaxf(fmaf((float)i8[j], scale[96 + cdx], shift[96 + cdx]), 0.f);
    outv[j] = (f16)sqrtf(rr * rr + ii * ii);
  }
  int c8s = (c8 & ~3) | ((c8 ^ (w >> 1)) & 3);
  *(f16x8*)(mg + (size_t)p * 96 + c8s * 8) = outv;
}

// ------------------------------------------------------------------------------
extern "C" void kernel_launch(void* const* d_in, const int* in_sizes, int n_in,
                              void* d_out, int out_size, void* d_ws, size_t ws_size,
                              hipStream_t stream) {
  const float* x   = (const float*)d_in[0];
  const float* w1r = (const float*)d_in[1];
  const float* w1i = (const float*)d_in[2];
  const float* g1  = (const float*)d_in[3];
  const float* b1  = (const float*)d_in[4];
  const float* w2r = (const float*)d_in[5];
  const float* w2i = (const float*)d_in[6];
  const float* g2  = (const float*)d_in[7];
  const float* b2  = (const float*)d_in[8];
  const float* w3r = (const float*)d_in[9];
  const float* w3i = (const float*)d_in[10];
  const float* g3  = (const float*)d_in[11];
  const float* b3  = (const float*)d_in[12];
  const float* w4r = (const float*)d_in[13];
  const float* w4i = (const float*)d_in[14];
  const float* g4  = (const float*)d_in[15];
  const float* b4  = (const float*)d_in[16];
  const float* wc  = (const float*)d_in[17];
  const float* bcp = (const float*)d_in[18];
  const float* wg  = (const float*)d_in[19];
  const float* bgp = (const float*)d_in[20];
  float* out = (float*)d_out;

  char* ws = (char*)d_ws;
  if (ws_size < 137500000ULL) return;

  char* zerop = ws;                              // 16KB zero page
  auto S  = [&](int L) { return (float*)(ws + 16384 + L * 4096); };
  auto Q  = [&](int L) { return (float*)(ws + 16384 + L * 4096) + 512; };
  auto SC = [&](int L) { return (float*)(ws + 32768 + L * 4096); };
  auto SH = [&](int L) { return (float*)(ws + 32768 + L * 4096) + 512; };
  f16* A1 = (f16*)(ws + 65536);
  f16* A2 = (f16*)(ws + 1392640);
  f16* A3 = (f16*)(ws + 2387968);
  f16* A4 = (f16*)(ws + 3051520);
  f16* AH = (f16*)(ws + 3715072);
  f16* XB0 = (f16*)(ws + (8ULL << 20));
  f16* Y   = (f16*)(ws + (68ULL << 20));

  hipMemsetAsync(d_ws, 0, 49152, stream);  // zero page + stats sums

  k_pack_x<<<P_TOT * 32 / 256, 256, 0, stream>>>(x, XB0);
  k_pack_w<<<(663552 + 255) / 256, 256, 0, stream>>>(w1r, w1i, A1, 0, 288, 256, 144, 256, 663552);
  k_pack_w<<<(497664 + 255) / 256, 256, 0, stream>>>(w2r, w2i, A2, 1, 192, 288, 96, 144, 497664);
  k_pack_w<<<(331776 + 255) / 256, 256, 0, stream>>>(w3r, w3i, A3, 1, 192, 192, 96, 96, 331776);
  k_pack_w<<<(331776 + 255) / 256, 256, 0, stream>>>(w4r, w4i, A4, 1, 192, 192, 96, 96, 331776);
  k_pack_w<<<(13824 + 255) / 256, 256, 0, stream>>>(wc, wg, AH, 2, 16, 96, 0, 96, 13824);

  // L1: 256 -> 288
  k_gemm<96, 288, 256, 2, 2, false><<<1536, 256, 0, stream>>>(XB0, A1, zerop, Y, nullptr, nullptr, nullptr, S(0), Q(0));
  k_finalize<<<1, 512, 0, stream>>>(S(0), Q(0), g1, b1, SC(0), SH(0), 288, 144);
  k_packip<288><<<P_TOT * 9 / 256, 256, 0, stream>>>(Y, SC(0), SH(0));

  // L2: 288 -> 192
  k_gemm<96, 192, 288, 2, 2, false><<<1024, 256, 0, stream>>>(Y, A2, zerop, XB0, nullptr, nullptr, nullptr, S(1), Q(1));
  k_finalize<<<1, 512, 0, stream>>>(S(1), Q(1), g2, b2, SC(1), SH(1), 192, 96);
  k_packip<192><<<P_TOT * 6 / 256, 256, 0, stream>>>(XB0, SC(1), SH(1));

  // L3: 192 -> 192
  k_gemm<96, 192, 192, 2, 2, false><<<1024, 256, 0, stream>>>(XB0, A3, zerop, Y, nullptr, nullptr, nullptr, S(2), Q(2));
  k_finalize<<<1, 512, 0, stream>>>(S(2), Q(2), g3, b3, SC(2), SH(2), 192, 96);
  k_packip<192><<<P_TOT * 6 / 256, 256, 0, stream>>>(Y, SC(2), SH(2));

  // L4: 192 -> 192
  k_gemm<96, 192, 192, 2, 2, false><<<1024, 256, 0, stream>>>(Y, A4, zerop, XB0, nullptr, nullptr, nullptr, S(3), Q(3));
  k_finalize<<<1, 512, 0, stream>>>(S(3), Q(3), g4, b4, SC(3), SH(3), 192, 96);

  // BN+ReLU+magnitude -> 96ch head input
  k_mag<<<P_TOT * 12 / 256, 256, 0, stream>>>(XB0, SC(3), SH(3), Y);

  // head: 96 -> 3 (sigmoid on ch0), writes NCHW fp32 output
  k_gemm<16, 16, 96, 1, 2, true><<<512, 128, 0, stream>>>(Y, AH, zerop, nullptr, out, bcp, bgp, nullptr, nullptr);

  (void)in_sizes; (void)n_in; (void)out_size;
}

// Round 5
// 901.371 us; speedup vs baseline: 1.7547x; 1.1196x over previous
//
#include <hip/hip_runtime.h>
#include <cstdint>
#include <cstddef>

#define P_TOT 114688   // N*H*W = 4*128*224
#define W_IMG 224
#define H_IMG 128

typedef _Float16 f16;
typedef __attribute__((ext_vector_type(8))) _Float16 f16x8;
typedef __attribute__((ext_vector_type(4))) _Float16 f16x4;
typedef __attribute__((ext_vector_type(2))) _Float16 f16x2;
typedef __attribute__((ext_vector_type(4))) float f32x4;

#define WAITVM(N) asm volatile("s_waitcnt vmcnt(" #N ")" ::: "memory")

__device__ __forceinline__ void barrier_sync() {
  asm volatile("" ::: "memory");
  __builtin_amdgcn_s_barrier();
  asm volatile("" ::: "memory");
}

__device__ __forceinline__ void gload16(const void* g, void* l) {
  __builtin_amdgcn_global_load_lds((const __attribute__((address_space(1))) void*)g,
                                   (__attribute__((address_space(3))) void*)l, 16, 0, 0);
}

// ---------------- pack input: fp32 NCHW -> fp16 NHWC, chunk-swizzled -------------
// stored slot = true_chunk ^ ((w>>1)&3) within each 32-ch group.
// Block: 512 threads = 16 consecutive pixels x 32 c8-groups (coalesced plane reads).
__global__ void k_pack_x(const float* __restrict__ x, f16* __restrict__ xb) {
  int tid = threadIdx.x;
  int pw  = tid & 15;
  int c8  = tid >> 4;                 // 0..31
  int p   = blockIdx.x * 16 + pw;     // grid = P_TOT/16
  int w   = p % W_IMG;
  int h   = (p / W_IMG) % H_IMG;
  int n   = p / (H_IMG * W_IMG);
  const float* src = x + ((size_t)(n * 256 + c8 * 8) * H_IMG + h) * W_IMG + w;
  f16x8 v;
#pragma unroll
  for (int j = 0; j < 8; j++) v[j] = (f16)src[(size_t)j * (H_IMG * W_IMG)];
  int c8s = (c8 & ~3) | ((c8 ^ (w >> 1)) & 3);
  *(f16x8*)(xb + (size_t)p * 256 + c8s * 8) = v;
}

// ---------------- pack weights into [q][OT][32] (q = kk*CC+c), swizzled ----------
__global__ void k_pack_w(const float* __restrict__ wa, const float* __restrict__ wb,
                         f16* __restrict__ dst, int mode, int OT, int CS,
                         int Coh, int Cih, int total) {
  int gid = blockIdx.x * 256 + threadIdx.x;
  if (gid >= total) return;
  int j  = gid & 31;
  int t1 = gid >> 5;
  int o  = t1 % OT;
  int t2 = t1 / OT;
  int CCc = CS >> 5;
  int cc = t2 % CCc;
  int kk = t2 / CCc;
  int chunkT = ((j >> 3) ^ (o >> 1)) & 3;   // stored slot holds true chunk slot^key
  int is = cc * 32 + chunkT * 8 + (j & 7);
  float val = 0.f;
  if (mode == 0) {
    val = (o < Coh) ? wa[((size_t)o * Cih + is) * 9 + kk]
                    : wb[((size_t)(o - Coh) * Cih + is) * 9 + kk];
  } else if (mode == 1) {
    if (o < Coh) {
      val = (is < Cih) ? wa[((size_t)o * Cih + is) * 9 + kk]
                       : -wb[((size_t)o * Cih + (is - Cih)) * 9 + kk];
    } else {
      int oo = o - Coh;
      val = (is < Cih) ? wb[((size_t)oo * Cih + is) * 9 + kk]
                       : wa[((size_t)oo * Cih + (is - Cih)) * 9 + kk];
    }
  } else {
    if (o == 0)      val = wa[(size_t)is * 9 + kk];
    else if (o == 1) val = wb[(size_t)is * 9 + kk];
    else if (o == 2) val = wb[(size_t)(96 + is) * 9 + kk];
  }
  dst[gid] = (f16)val;
}

// ---------------- implicit-GEMM conv: BK=64/stage, setprio MFMA clusters --------
template<int BM, int OT, int CS, int WM, int WN, bool HEAD>
__launch_bounds__(WM * WN * 64)
__global__ void k_gemm(const f16* __restrict__ xb, const f16* __restrict__ Apack,
                       const char* __restrict__ zerop,
                       f16* __restrict__ y, float* __restrict__ outh,
                       const float* __restrict__ bcp, const float* __restrict__ bgp,
                       float* __restrict__ sums, float* __restrict__ sumsq) {
  constexpr int NT = WM * WN * 64;
  constexpr int NWV = NT / 64;
  constexpr int CC = CS / 32;
  constexpr int MF = BM / (WM * 16);
  constexpr int NF = 224 / (WN * 16);
  constexpr int NCH = 9 * CC;             // total K chunks of 32
  constexpr int TILE1 = (BM + 224) * 32;  // f16 per half (A then B)
  constexpr int ACH = BM * 64 / 1024;     // A 1KB-chunks per half (=BM/16)
  constexpr int TCH = ACH + 14;           // 1KB-chunks per half
  constexpr int NHALF = HEAD ? 1 : 2;
  static_assert(HEAD || (TCH % NWV == 0 && TCH / NWV == 5), "vmcnt math: 5 loads/thread/half");
  __shared__ f16 lds[2][NHALF * TILE1];

  constexpr int NOT = OT / BM;
  constexpr int nwg = NOT * 512;
  int bid = blockIdx.x;
  int swz = (bid & 7) * (nwg >> 3) + (bid >> 3);  // XCD swizzle (nwg % 8 == 0)
  const int ot = swz % NOT;                        // ot fastest -> same-B blocks adjacent
  const int rq = swz / NOT;
  const int n = rq >> 7;
  const int h = rq & 127;
  const int tid  = threadIdx.x;
  const int lane = tid & 63;
  const int wv   = tid >> 6;
  const int wm   = wv % WM;
  const int wn   = wv / WM;
  const int obase  = wm * (MF * 16);
  const int wnbase = wn * (NF * 16);
  const int l15 = lane & 15;
  const int lhi = lane >> 4;
  // A frag: row stride 64B; slot = lhi ^ ((row>>1)&3) -> <=2-way bank aliasing (free)
  const int aoff = l15 * 64 + (((lhi ^ (l15 >> 1)) & 3) << 4);

  f32x4 acc[MF][NF];
#pragma unroll
  for (int mi = 0; mi < MF; mi++)
#pragma unroll
    for (int ni = 0; ni < NF; ni++) acc[mi][ni] = (f32x4){0.f, 0.f, 0.f, 0.f};

  const size_t rowstride = (size_t)CS * 2;   // bytes per pixel in xb

  // stage one K-chunk q into LDS at `base` (TCH KB; 5 gloads/thread for !HEAD)
  auto stage1 = [&](char* base, int q) {
    const int kk = q / CC, c = q % CC;
    const char* asrc = (const char*)(Apack + ((size_t)q * OT + ot * BM) * 32);
    const int dh = kk / 3 - 1;
    const int dw = kk % 3 - 1;
    const int hp = h + dh;
    const bool hok = (hp >= 0) && (hp < H_IMG);
    const int hpc = hok ? hp : 0;
    const char* brow = (const char*)xb + ((size_t)(n * H_IMG + hpc) * W_IMG) * rowstride + c * 64;
#pragma unroll
    for (int ck = wv; ck < TCH; ck += NWV) {
      char* dst = base + ck * 1024;           // wave-uniform
      if (ck < ACH) {
        gload16(asrc + ck * 1024 + lane * 16, dst);
      } else {
        int bidx = ck - ACH;
        int px = bidx * 16 + (lane >> 2);
        int ch = lane & 3;
        int wp = px + dw;
        bool ok = hok && ((unsigned)wp < 224u);
        const char* src = ok ? brow + (size_t)wp * rowstride + ch * 16
                             : zerop + ch * 16;
        gload16(src, dst);
      }
    }
  };

  // compute one staged K-chunk at `base` (kk for the B swizzle key)
  auto compute_half = [&](const char* base, int kk) {
    const int dw = kk % 3 - 1;
    const char* Ab = base;
    const char* Bb = base + BM * 64;
    f16x8 af[MF], bfr[NF];
#pragma unroll
    for (int mi = 0; mi < MF; mi++)
      af[mi] = *(const f16x8*)(Ab + (obase + mi * 16) * 64 + aoff);
#pragma unroll
    for (int ni = 0; ni < NF; ni++) {
      int px = wnbase + ni * 16 + l15;
      int sw = ((lhi ^ ((px + dw) >> 1)) & 3) << 4;
      bfr[ni] = *(const f16x8*)(Bb + px * 64 + sw);
    }
    __builtin_amdgcn_s_setprio(1);
#pragma unroll
    for (int mi = 0; mi < MF; mi++)
#pragma unroll
      for (int ni = 0; ni < NF; ni++)
        acc[mi][ni] = __builtin_amdgcn_mfma_f32_16x16x32_f16(af[mi], bfr[ni], acc[mi][ni], 0, 0, 0);
    __builtin_amdgcn_s_setprio(0);
  };

  if constexpr (!HEAD) {
    constexpr int STEPS = (NCH + 1) / 2;
    auto stage_pair = [&](int buf, int q) {
      char* b = (char*)&lds[buf][0];
      int q1 = (q + 1 < NCH) ? (q + 1) : (NCH - 1);   // dummy re-stage on odd tail
      stage1(b, q);
      stage1(b + TILE1 * 2, q1);
    };
    stage_pair(0, 0);
    for (int s = 0; s < STEPS; ++s) {
      int qn = (s + 1) * 2;
      if (qn < NCH) { stage_pair((s + 1) & 1, qn); WAITVM(10); }
      else          { WAITVM(0); }
      barrier_sync();
      const char* b = (const char*)&lds[s & 1][0];
      int q = s * 2;
      compute_half(b, q / CC);
      if (q + 1 < NCH) compute_half(b + TILE1 * 2, (q + 1) / CC);
      barrier_sync();
    }
  } else {
    stage1((char*)&lds[0][0], 0);
    __syncthreads();
    int buf = 0;
    for (int t = 0; t < NCH; ++t) {
      int tn = t + 1;
      if (tn < NCH) stage1((char*)&lds[buf ^ 1][0], tn);
      compute_half((const char*)&lds[buf][0], t / CC);
      __syncthreads();
      buf ^= 1;
    }
  }

  const size_t prow = (size_t)(n * H_IMG + h) * W_IMG;
  if constexpr (!HEAD) {
    // store fp16 NHWC output
#pragma unroll
    for (int mi = 0; mi < MF; mi++) {
#pragma unroll
      for (int ni = 0; ni < NF; ni++) {
        int o = obase + mi * 16 + lhi * 4;
        int w = wnbase + ni * 16 + l15;
        f16x4 v4;
#pragma unroll
        for (int j = 0; j < 4; j++) v4[j] = (f16)acc[mi][ni][j];
        *(f16x4*)(y + (prow + w) * OT + ot * BM + o) = v4;
      }
    }
    // fused BN stats: per-channel sum / sumsq partials
    float sv[MF][4], qv[MF][4];
#pragma unroll
    for (int mi = 0; mi < MF; mi++)
#pragma unroll
      for (int j = 0; j < 4; j++) {
        float s = 0.f, q = 0.f;
#pragma unroll
        for (int ni = 0; ni < NF; ni++) {
          float v = acc[mi][ni][j];
          s += v; q += v * v;
        }
        sv[mi][j] = s; qv[mi][j] = q;
      }
#pragma unroll
    for (int m = 1; m < 16; m <<= 1) {
#pragma unroll
      for (int mi = 0; mi < MF; mi++)
#pragma unroll
        for (int j = 0; j < 4; j++) {
          sv[mi][j] += __shfl_xor(sv[mi][j], m);
          qv[mi][j] += __shfl_xor(qv[mi][j], m);
        }
    }
    if (l15 == 0) {
#pragma unroll
      for (int mi = 0; mi < MF; mi++)
#pragma unroll
        for (int j = 0; j < 4; j++) {
          int ch = ot * BM + obase + mi * 16 + lhi * 4 + j;
          atomicAdd(&sums[ch], sv[mi][j]);
          atomicAdd(&sumsq[ch], qv[mi][j]);
        }
    }
  } else {
    if (lhi == 0) {
      float b0 = bcp[0], b1 = bgp[0], b2 = bgp[1];
#pragma unroll
      for (int ni = 0; ni < NF; ni++) {
        int w = wnbase + ni * 16 + l15;
        float c0 = acc[0][ni][0] + b0;
        c0 = 1.f / (1.f + expf(-c0));
        float c1 = acc[0][ni][1] + b1;
        float c2 = acc[0][ni][2] + b2;
        outh[((size_t)(n * 3 + 0) * H_IMG + h) * W_IMG + w] = c0;
        outh[((size_t)(n * 3 + 1) * H_IMG + h) * W_IMG + w] = c1;
        outh[((size_t)(n * 3 + 2) * H_IMG + h) * W_IMG + w] = c2;
      }
    }
  }
}

// ---------------- BN coefficient recompute (fused into consumers) ---------------
template<int O>
__device__ __forceinline__ void bn_coef(const float* __restrict__ sums,
                                        const float* __restrict__ sumsq,
                                        const float* __restrict__ g,
                                        const float* __restrict__ b,
                                        float* sc, float* sh, int tid, int nt) {
  const float inv = 1.0f / (float)P_TOT;
  for (int t = tid; t < O; t += nt) {
    float mean = sums[t] * inv;
    float var  = fmaxf(sumsq[t] * inv - mean * mean, 0.f);
    int gi = (t < O / 2) ? t : (t - O / 2);
    float s = g[gi] * rsqrtf(var + 1e-5f);
    sc[t] = s;
    sh[t] = b[gi] - mean * s;
  }
}

// ---------------- in-place BN + ReLU + chunk-swizzle (finalize fused) -----------
template<int O>
__global__ void k_packip(f16* __restrict__ y,
                         const float* __restrict__ sums, const float* __restrict__ sumsq,
                         const float* __restrict__ g, const float* __restrict__ b) {
  __shared__ float sc[O], sh[O];
  bn_coef<O>(sums, sumsq, g, b, sc, sh, threadIdx.x, 256);
  __syncthreads();
  constexpr int G32 = O / 32;
  int gid = blockIdx.x * 256 + threadIdx.x;
  if (gid >= P_TOT * G32) return;
  int gg = gid % G32;
  int p = gid / G32;
  int w = p % W_IMG;
  f16* base = y + (size_t)p * O + gg * 32;
  f16x8 in[4];
#pragma unroll
  for (int ch = 0; ch < 4; ch++) in[ch] = *(const f16x8*)(base + ch * 8);
  int sw = (w >> 1) & 3;
  f16x8 outv[4];
#pragma unroll
  for (int ch = 0; ch < 4; ch++) {
#pragma unroll
    for (int j = 0; j < 8; j++) {
      int cdx = gg * 32 + ch * 8 + j;
      float f = fmaxf(fmaf((float)in[ch][j], sc[cdx], sh[cdx]), 0.f);
      outv[ch][j] = (f16)f;
    }
  }
#pragma unroll
  for (int ch = 0; ch < 4; ch++) *(f16x8*)(base + ((ch ^ sw) & 3) * 8) = outv[ch];
}

// ---------------- BN(L4) + ReLU + complex magnitude -> 96ch swizzled ------------
__global__ void k_mag(const f16* __restrict__ y,
                      const float* __restrict__ sums, const float* __restrict__ sumsq,
                      const float* __restrict__ g, const float* __restrict__ b,
                      f16* __restrict__ mg) {
  __shared__ float sc[192], sh[192];
  bn_coef<192>(sums, sumsq, g, b, sc, sh, threadIdx.x, 256);
  __syncthreads();
  int gid = blockIdx.x * 256 + threadIdx.x;
  if (gid >= P_TOT * 12) return;
  int c8 = gid % 12;
  int p  = gid / 12;
  int w  = p % W_IMG;
  f16x8 r8 = *(const f16x8*)(y + (size_t)p * 192 + c8 * 8);
  f16x8 i8 = *(const f16x8*)(y + (size_t)p * 192 + 96 + c8 * 8);
  f16x8 outv;
#pragma unroll
  for (int j = 0; j < 8; j++) {
    int cdx = c8 * 8 + j;
    float rr = fmaxf(fmaf((float)r8[j], sc[cdx], sh[cdx]), 0.f);
    float ii = fmaxf(fmaf((float)i8[j], sc[96 + cdx], sh[96 + cdx]), 0.f);
    outv[j] = (f16)sqrtf(rr * rr + ii * ii);
  }
  int c8s = (c8 & ~3) | ((c8 ^ (w >> 1)) & 3);
  *(f16x8*)(mg + (size_t)p * 96 + c8s * 8) = outv;
}

// ------------------------------------------------------------------------------
extern "C" void kernel_launch(void* const* d_in, const int* in_sizes, int n_in,
                              void* d_out, int out_size, void* d_ws, size_t ws_size,
                              hipStream_t stream) {
  const float* x   = (const float*)d_in[0];
  const float* w1r = (const float*)d_in[1];
  const float* w1i = (const float*)d_in[2];
  const float* g1  = (const float*)d_in[3];
  const float* b1  = (const float*)d_in[4];
  const float* w2r = (const float*)d_in[5];
  const float* w2i = (const float*)d_in[6];
  const float* g2  = (const float*)d_in[7];
  const float* b2  = (const float*)d_in[8];
  const float* w3r = (const float*)d_in[9];
  const float* w3i = (const float*)d_in[10];
  const float* g3  = (const float*)d_in[11];
  const float* b3  = (const float*)d_in[12];
  const float* w4r = (const float*)d_in[13];
  const float* w4i = (const float*)d_in[14];
  const float* g4  = (const float*)d_in[15];
  const float* b4  = (const float*)d_in[16];
  const float* wc  = (const float*)d_in[17];
  const float* bcp = (const float*)d_in[18];
  const float* wg  = (const float*)d_in[19];
  const float* bgp = (const float*)d_in[20];
  float* out = (float*)d_out;

  char* ws = (char*)d_ws;
  if (ws_size < 137500000ULL) return;

  char* zerop = ws;                              // 16KB zero page
  auto S  = [&](int L) { return (float*)(ws + 16384 + L * 4096); };
  auto Q  = [&](int L) { return (float*)(ws + 16384 + L * 4096) + 512; };
  f16* A1 = (f16*)(ws + 65536);
  f16* A2 = (f16*)(ws + 1392640);
  f16* A3 = (f16*)(ws + 2387968);
  f16* A4 = (f16*)(ws + 3051520);
  f16* AH = (f16*)(ws + 3715072);
  f16* XB0 = (f16*)(ws + (8ULL << 20));
  f16* Y   = (f16*)(ws + (68ULL << 20));

  hipMemsetAsync(d_ws, 0, 49152, stream);  // zero page + stats sums

  k_pack_x<<<P_TOT / 16, 512, 0, stream>>>(x, XB0);
  k_pack_w<<<(663552 + 255) / 256, 256, 0, stream>>>(w1r, w1i, A1, 0, 288, 256, 144, 256, 663552);
  k_pack_w<<<(497664 + 255) / 256, 256, 0, stream>>>(w2r, w2i, A2, 1, 192, 288, 96, 144, 497664);
  k_pack_w<<<(331776 + 255) / 256, 256, 0, stream>>>(w3r, w3i, A3, 1, 192, 192, 96, 96, 331776);
  k_pack_w<<<(331776 + 255) / 256, 256, 0, stream>>>(w4r, w4i, A4, 1, 192, 192, 96, 96, 331776);
  k_pack_w<<<(13824 + 255) / 256, 256, 0, stream>>>(wc, wg, AH, 2, 16, 96, 0, 96, 13824);

  // L1: 256 -> 288
  k_gemm<96, 288, 256, 2, 2, false><<<1536, 256, 0, stream>>>(XB0, A1, zerop, Y, nullptr, nullptr, nullptr, S(0), Q(0));
  k_packip<288><<<P_TOT * 9 / 256, 256, 0, stream>>>(Y, S(0), Q(0), g1, b1);

  // L2: 288 -> 192
  k_gemm<96, 192, 288, 2, 2, false><<<1024, 256, 0, stream>>>(Y, A2, zerop, XB0, nullptr, nullptr, nullptr, S(1), Q(1));
  k_packip<192><<<P_TOT * 6 / 256, 256, 0, stream>>>(XB0, S(1), Q(1), g2, b2);

  // L3: 192 -> 192
  k_gemm<96, 192, 192, 2, 2, false><<<1024, 256, 0, stream>>>(XB0, A3, zerop, Y, nullptr, nullptr, nullptr, S(2), Q(2));
  k_packip<192><<<P_TOT * 6 / 256, 256, 0, stream>>>(Y, S(2), Q(2), g3, b3);

  // L4: 192 -> 192
  k_gemm<96, 192, 192, 2, 2, false><<<1024, 256, 0, stream>>>(Y, A4, zerop, XB0, nullptr, nullptr, nullptr, S(3), Q(3));

  // BN+ReLU+magnitude -> 96ch head input (finalize fused)
  k_mag<<<P_TOT * 12 / 256, 256, 0, stream>>>(XB0, S(3), Q(3), g4, b4, Y);

  // head: 96 -> 3 (sigmoid on ch0), writes NCHW fp32 output
  k_gemm<16, 16, 96, 1, 2, true><<<512, 128, 0, stream>>>(Y, AH, zerop, nullptr, out, bcp, bgp, nullptr, nullptr);

  (void)in_sizes; (void)n_in; (void)out_size;
}

// Round 6
// 883.728 us; speedup vs baseline: 1.7897x; 1.0200x over previous
//
#include <hip/hip_runtime.h>
#include <cstdint>
#include <cstddef>

#define P_TOT 114688   // N*H*W = 4*128*224
#define W_IMG 224
#define H_IMG 128
#define WP 228         // padded row width (1 left, 3 right)
#define HP 130         // padded rows (1 top, 1 bottom)

typedef _Float16 f16;
typedef __attribute__((ext_vector_type(8))) _Float16 f16x8;
typedef __attribute__((ext_vector_type(4))) _Float16 f16x4;
typedef __attribute__((ext_vector_type(4))) float f32x4;

#define WAITVM(N) asm volatile("s_waitcnt vmcnt(" #N ")" ::: "memory")

__device__ __forceinline__ void barrier_sync() {
  asm volatile("" ::: "memory");
  __builtin_amdgcn_s_barrier();
  asm volatile("" ::: "memory");
}

__device__ __forceinline__ void gload16(const void* g, void* l) {
  __builtin_amdgcn_global_load_lds((const __attribute__((address_space(1))) void*)g,
                                   (__attribute__((address_space(3))) void*)l, 16, 0, 0);
}

__device__ __forceinline__ size_t pad_px(int n, int h, int w) {
  return ((size_t)(n * HP + h + 1)) * WP + (w + 1);
}

// ---------------- zero the halo pixels of a padded slab --------------------------
__global__ void k_halo(f16* __restrict__ slab, int CS) {
  int c8n = CS >> 3;
  int tid = blockIdx.x * 256 + threadIdx.x;
  int c8 = tid % c8n;
  int rest = tid / c8n;
  if (rest >= 4 * 968) return;
  int n = rest / 968, i = rest % 968;
  int h, w;
  if (i < 456) { h = (i < 228) ? 0 : 129; w = i % 228; }
  else { int j = i - 456; h = 1 + (j >> 2); int k = j & 3; w = (k == 0) ? 0 : (224 + k); }
  size_t pp = ((size_t)(n * HP + h)) * WP + w;
  *(f16x8*)(slab + pp * CS + c8 * 8) = (f16x8){0, 0, 0, 0, 0, 0, 0, 0};
}

// ---------------- pack input: fp32 NCHW -> fp16 padded-NHWC, chunk-swizzled ------
// stored slot = true_chunk ^ ((w>>1)&3) within each 32-ch group.
__global__ void k_pack_x(const float* __restrict__ x, f16* __restrict__ xb) {
  int tid = threadIdx.x;
  int pw  = tid & 15;
  int c8  = tid >> 4;                 // 0..31
  int p   = blockIdx.x * 16 + pw;     // grid = P_TOT/16
  int w   = p % W_IMG;
  int h   = (p / W_IMG) % H_IMG;
  int n   = p / (H_IMG * W_IMG);
  const float* src = x + ((size_t)(n * 256 + c8 * 8) * H_IMG + h) * W_IMG + w;
  f16x8 v;
#pragma unroll
  for (int j = 0; j < 8; j++) v[j] = (f16)src[(size_t)j * (H_IMG * W_IMG)];
  int c8s = (c8 & ~3) | ((c8 ^ (w >> 1)) & 3);
  *(f16x8*)(xb + pad_px(n, h, w) * 256 + c8s * 8) = v;
}

// ---------------- pack weights into [q][OT][32] (q = kk*CC+c), swizzled ----------
__global__ void k_pack_w(const float* __restrict__ wa, const float* __restrict__ wb,
                         f16* __restrict__ dst, int mode, int OT, int CS,
                         int Coh, int Cih, int total) {
  int gid = blockIdx.x * 256 + threadIdx.x;
  if (gid >= total) return;
  int j  = gid & 31;
  int t1 = gid >> 5;
  int o  = t1 % OT;
  int t2 = t1 / OT;
  int CCc = CS >> 5;
  int cc = t2 % CCc;
  int kk = t2 / CCc;
  int chunkT = ((j >> 3) ^ (o >> 1)) & 3;   // stored slot holds true chunk slot^key
  int is = cc * 32 + chunkT * 8 + (j & 7);
  float val = 0.f;
  if (mode == 0) {
    val = (o < Coh) ? wa[((size_t)o * Cih + is) * 9 + kk]
                    : wb[((size_t)(o - Coh) * Cih + is) * 9 + kk];
  } else if (mode == 1) {
    if (o < Coh) {
      val = (is < Cih) ? wa[((size_t)o * Cih + is) * 9 + kk]
                       : -wb[((size_t)o * Cih + (is - Cih)) * 9 + kk];
    } else {
      int oo = o - Coh;
      val = (is < Cih) ? wb[((size_t)oo * Cih + is) * 9 + kk]
                       : wa[((size_t)oo * Cih + (is - Cih)) * 9 + kk];
    }
  } else {
    if (o == 0)      val = wa[(size_t)is * 9 + kk];
    else if (o == 1) val = wb[(size_t)is * 9 + kk];
    else if (o == 2) val = wb[(size_t)(96 + is) * 9 + kk];
  }
  dst[gid] = (f16)val;
}

// ---------------- implicit-GEMM conv: branch-free halo staging ------------------
template<int BM, int OT, int CS, int WM, int WN, bool HEAD>
__launch_bounds__(WM * WN * 64)
__global__ void k_gemm(const f16* __restrict__ xb, const f16* __restrict__ Apack,
                       f16* __restrict__ y, float* __restrict__ outh,
                       const float* __restrict__ bcp, const float* __restrict__ bgp,
                       float* __restrict__ sums, float* __restrict__ sumsq) {
  constexpr int NT = WM * WN * 64;
  constexpr int NWV = NT / 64;
  constexpr int CC = CS / 32;
  constexpr int MF = BM / (WM * 16);
  constexpr int NF = 224 / (WN * 16);
  constexpr int NCH = 9 * CC;             // total K chunks of 32
  constexpr int TILE1 = (BM + 224) * 32;  // f16 per half (A then B)
  constexpr int ACH = BM / 16;            // A 1KB-chunks per half
  constexpr int TCH = ACH + 14;           // 1KB-chunks per half
  constexpr int NHALF = HEAD ? 1 : 2;
  static_assert(HEAD || (TCH % NWV == 0 && TCH / NWV == 5), "vmcnt math: 5 loads/thread/half");
  __shared__ f16 lds[2][NHALF * TILE1];

  constexpr int NOT = OT / BM;
  constexpr int nwg = NOT * 512;
  int bid = blockIdx.x;
  int swz = (bid & 7) * (nwg >> 3) + (bid >> 3);  // XCD swizzle (nwg % 8 == 0)
  const int ot = swz % NOT;                        // ot fastest -> same-B blocks adjacent
  const int rq = swz / NOT;
  const int n = rq >> 7;
  const int h = rq & 127;
  const int tid  = threadIdx.x;
  const int lane = tid & 63;
  const int wv   = tid >> 6;
  const int wm   = wv % WM;
  const int wn   = wv / WM;
  const int obase  = wm * (MF * 16);
  const int wnbase = wn * (NF * 16);
  const int l15 = lane & 15;
  const int lhi = lane >> 4;
  // A frag: row stride 64B; slot = lhi ^ ((row>>1)&3) -> <=2-way bank aliasing (free)
  const int aoff = l15 * 64 + (((lhi ^ (l15 >> 1)) & 3) << 4);

  f32x4 acc[MF][NF];
#pragma unroll
  for (int mi = 0; mi < MF; mi++)
#pragma unroll
    for (int ni = 0; ni < NF; ni++) acc[mi][ni] = (f32x4){0.f, 0.f, 0.f, 0.f};

  // hoisted per-thread staging bases (branch-free: halo is pre-zeroed)
  const char* abase = (const char*)Apack + (size_t)ot * BM * 64 + lane * 16;
  const char* bbase = (const char*)xb +
      (pad_px(n, h, 0) + (lane >> 2)) * (CS * 2) + (lane & 3) * 16;

  // stage one K-chunk q into LDS at `base` (TCH KB)
  auto stage1 = [&](char* base, int q) {
    const int kk = q / CC, c = q % CC;
    const int dh = kk / 3 - 1;
    const int dw = kk % 3 - 1;
    const char* asrc = abase + (size_t)q * (OT * 64);
    const char* bsrc = bbase + (dh * WP + dw) * (int)(CS * 2) + c * 64;
#pragma unroll
    for (int ck = wv; ck < TCH; ck += NWV) {
      char* dst = base + ck * 1024;           // wave-uniform
      if (ck < ACH) gload16(asrc + ck * 1024, dst);
      else          gload16(bsrc + (size_t)(ck - ACH) * (16 * CS * 2), dst);
    }
  };

  // compute one staged K-chunk at `base` (kk for the B swizzle key)
  auto compute_half = [&](const char* base, int kk) {
    const int dw = kk % 3 - 1;
    const char* Ab = base;
    const char* Bb = base + BM * 64;
    f16x8 af[MF], bfr[NF];
#pragma unroll
    for (int mi = 0; mi < MF; mi++)
      af[mi] = *(const f16x8*)(Ab + (obase + mi * 16) * 64 + aoff);
#pragma unroll
    for (int ni = 0; ni < NF; ni++) {
      int px = wnbase + ni * 16 + l15;
      int sw = ((lhi ^ ((px + dw) >> 1)) & 3) << 4;
      bfr[ni] = *(const f16x8*)(Bb + px * 64 + sw);
    }
    __builtin_amdgcn_s_setprio(1);
#pragma unroll
    for (int mi = 0; mi < MF; mi++)
#pragma unroll
      for (int ni = 0; ni < NF; ni++)
        acc[mi][ni] = __builtin_amdgcn_mfma_f32_16x16x32_f16(af[mi], bfr[ni], acc[mi][ni], 0, 0, 0);
    __builtin_amdgcn_s_setprio(0);
  };

  if constexpr (!HEAD) {
    constexpr int STEPS = (NCH + 1) / 2;
    auto stage_pair = [&](int buf, int q) {
      char* b = (char*)&lds[buf][0];
      int q1 = (q + 1 < NCH) ? (q + 1) : (NCH - 1);   // dummy re-stage on odd tail
      stage1(b, q);
      stage1(b + TILE1 * 2, q1);
    };
    stage_pair(0, 0);
    for (int s = 0; s < STEPS; ++s) {
      int qn = (s + 1) * 2;
      if (qn < NCH) { stage_pair((s + 1) & 1, qn); WAITVM(10); }
      else          { WAITVM(0); }
      barrier_sync();
      const char* b = (const char*)&lds[s & 1][0];
      int q = s * 2;
      compute_half(b, q / CC);
      if (q + 1 < NCH) compute_half(b + TILE1 * 2, (q + 1) / CC);
      barrier_sync();
    }
  } else {
    stage1((char*)&lds[0][0], 0);
    __syncthreads();
    int buf = 0;
    for (int t = 0; t < NCH; ++t) {
      int tn = t + 1;
      if (tn < NCH) stage1((char*)&lds[buf ^ 1][0], tn);
      compute_half((const char*)&lds[buf][0], t / CC);
      __syncthreads();
      buf ^= 1;
    }
  }

  if constexpr (!HEAD) {
    const size_t prow = pad_px(n, h, 0);
    // store fp16 padded-NHWC output
#pragma unroll
    for (int mi = 0; mi < MF; mi++) {
#pragma unroll
      for (int ni = 0; ni < NF; ni++) {
        int o = obase + mi * 16 + lhi * 4;
        int w = wnbase + ni * 16 + l15;
        f16x4 v4;
#pragma unroll
        for (int j = 0; j < 4; j++) v4[j] = (f16)acc[mi][ni][j];
        *(f16x4*)(y + (prow + w) * OT + ot * BM + o) = v4;
      }
    }
    // fused BN stats: per-channel sum / sumsq partials
    float sv[MF][4], qv[MF][4];
#pragma unroll
    for (int mi = 0; mi < MF; mi++)
#pragma unroll
      for (int j = 0; j < 4; j++) {
        float s = 0.f, q = 0.f;
#pragma unroll
        for (int ni = 0; ni < NF; ni++) {
          float v = acc[mi][ni][j];
          s += v; q += v * v;
        }
        sv[mi][j] = s; qv[mi][j] = q;
      }
#pragma unroll
    for (int m = 1; m < 16; m <<= 1) {
#pragma unroll
      for (int mi = 0; mi < MF; mi++)
#pragma unroll
        for (int j = 0; j < 4; j++) {
          sv[mi][j] += __shfl_xor(sv[mi][j], m);
          qv[mi][j] += __shfl_xor(qv[mi][j], m);
        }
    }
    if (l15 == 0) {
#pragma unroll
      for (int mi = 0; mi < MF; mi++)
#pragma unroll
        for (int j = 0; j < 4; j++) {
          int ch = ot * BM + obase + mi * 16 + lhi * 4 + j;
          atomicAdd(&sums[ch], sv[mi][j]);
          atomicAdd(&sumsq[ch], qv[mi][j]);
        }
    }
  } else {
    if (lhi == 0) {
      float b0 = bcp[0], b1 = bgp[0], b2 = bgp[1];
#pragma unroll
      for (int ni = 0; ni < NF; ni++) {
        int w = wnbase + ni * 16 + l15;
        float c0 = acc[0][ni][0] + b0;
        c0 = 1.f / (1.f + expf(-c0));
        float c1 = acc[0][ni][1] + b1;
        float c2 = acc[0][ni][2] + b2;
        outh[((size_t)(n * 3 + 0) * H_IMG + h) * W_IMG + w] = c0;
        outh[((size_t)(n * 3 + 1) * H_IMG + h) * W_IMG + w] = c1;
        outh[((size_t)(n * 3 + 2) * H_IMG + h) * W_IMG + w] = c2;
      }
    }
  }
}

// ---------------- BN coefficient recompute (fused into consumers) ---------------
template<int O>
__device__ __forceinline__ void bn_coef(const float* __restrict__ sums,
                                        const float* __restrict__ sumsq,
                                        const float* __restrict__ g,
                                        const float* __restrict__ b,
                                        float* sc, float* sh, int tid, int nt) {
  const float inv = 1.0f / (float)P_TOT;
  for (int t = tid; t < O; t += nt) {
    float mean = sums[t] * inv;
    float var  = fmaxf(sumsq[t] * inv - mean * mean, 0.f);
    int gi = (t < O / 2) ? t : (t - O / 2);
    float s = g[gi] * rsqrtf(var + 1e-5f);
    sc[t] = s;
    sh[t] = b[gi] - mean * s;
  }
}

// ---------------- in-place BN + ReLU + chunk-swizzle (finalize fused) -----------
template<int O>
__global__ void k_packip(f16* __restrict__ y,
                         const float* __restrict__ sums, const float* __restrict__ sumsq,
                         const float* __restrict__ g, const float* __restrict__ b) {
  __shared__ float sc[O], sh[O];
  bn_coef<O>(sums, sumsq, g, b, sc, sh, threadIdx.x, 256);
  __syncthreads();
  constexpr int G32 = O / 32;
  int gid = blockIdx.x * 256 + threadIdx.x;
  if (gid >= P_TOT * G32) return;
  int gg = gid % G32;
  int p = gid / G32;
  int w = p % W_IMG;
  int hh = (p / W_IMG) % H_IMG;
  int nn = p / (W_IMG * H_IMG);
  f16* base = y + pad_px(nn, hh, w) * O + gg * 32;
  f16x8 in[4];
#pragma unroll
  for (int ch = 0; ch < 4; ch++) in[ch] = *(const f16x8*)(base + ch * 8);
  int sw = (w >> 1) & 3;
  f16x8 outv[4];
#pragma unroll
  for (int ch = 0; ch < 4; ch++) {
#pragma unroll
    for (int j = 0; j < 8; j++) {
      int cdx = gg * 32 + ch * 8 + j;
      float f = fmaxf(fmaf((float)in[ch][j], sc[cdx], sh[cdx]), 0.f);
      outv[ch][j] = (f16)f;
    }
  }
#pragma unroll
  for (int ch = 0; ch < 4; ch++) *(f16x8*)(base + ((ch ^ sw) & 3) * 8) = outv[ch];
}

// ---------------- BN(L4) + ReLU + complex magnitude -> 96ch swizzled ------------
__global__ void k_mag(const f16* __restrict__ y,
                      const float* __restrict__ sums, const float* __restrict__ sumsq,
                      const float* __restrict__ g, const float* __restrict__ b,
                      f16* __restrict__ mg) {
  __shared__ float sc[192], sh[192];
  bn_coef<192>(sums, sumsq, g, b, sc, sh, threadIdx.x, 256);
  __syncthreads();
  int gid = blockIdx.x * 256 + threadIdx.x;
  if (gid >= P_TOT * 12) return;
  int c8 = gid % 12;
  int p  = gid / 12;
  int w  = p % W_IMG;
  int hh = (p / W_IMG) % H_IMG;
  int nn = p / (W_IMG * H_IMG);
  size_t pp = pad_px(nn, hh, w);
  f16x8 r8 = *(const f16x8*)(y + pp * 192 + c8 * 8);
  f16x8 i8 = *(const f16x8*)(y + pp * 192 + 96 + c8 * 8);
  f16x8 outv;
#pragma unroll
  for (int j = 0; j < 8; j++) {
    int cdx = c8 * 8 + j;
    float rr = fmaxf(fmaf((float)r8[j], sc[cdx], sh[cdx]), 0.f);
    float ii = fmaxf(fmaf((float)i8[j], sc[96 + cdx], sh[96 + cdx]), 0.f);
    outv[j] = (f16)sqrtf(rr * rr + ii * ii);
  }
  int c8s = (c8 & ~3) | ((c8 ^ (w >> 1)) & 3);
  *(f16x8*)(mg + pp * 96 + c8s * 8) = outv;
}

// ------------------------------------------------------------------------------
extern "C" void kernel_launch(void* const* d_in, const int* in_sizes, int n_in,
                              void* d_out, int out_size, void* d_ws, size_t ws_size,
                              hipStream_t stream) {
  const float* x   = (const float*)d_in[0];
  const float* w1r = (const float*)d_in[1];
  const float* w1i = (const float*)d_in[2];
  const float* g1  = (const float*)d_in[3];
  const float* b1  = (const float*)d_in[4];
  const float* w2r = (const float*)d_in[5];
  const float* w2i = (const float*)d_in[6];
  const float* g2  = (const float*)d_in[7];
  const float* b2  = (const float*)d_in[8];
  const float* w3r = (const float*)d_in[9];
  const float* w3i = (const float*)d_in[10];
  const float* g3  = (const float*)d_in[11];
  const float* b3  = (const float*)d_in[12];
  const float* w4r = (const float*)d_in[13];
  const float* w4i = (const float*)d_in[14];
  const float* g4  = (const float*)d_in[15];
  const float* b4  = (const float*)d_in[16];
  const float* wc  = (const float*)d_in[17];
  const float* bcp = (const float*)d_in[18];
  const float* wg  = (const float*)d_in[19];
  const float* bgp = (const float*)d_in[20];
  float* out = (float*)d_out;

  char* ws = (char*)d_ws;
  if (ws_size < 137500000ULL) return;

  auto S  = [&](int L) { return (float*)(ws + 16384 + L * 4096); };
  auto Q  = [&](int L) { return (float*)(ws + 16384 + L * 4096) + 512; };
  f16* A1 = (f16*)(ws + 65536);
  f16* A2 = (f16*)(ws + 1392640);
  f16* A3 = (f16*)(ws + 2387968);
  f16* A4 = (f16*)(ws + 3051520);
  f16* AH = (f16*)(ws + 3715072);
  f16* SLA = (f16*)(ws + 4194304);     // padded slab A: 118560 px * 256ch max = 60.7MB
  f16* SLB = (f16*)(ws + 65011712);    // padded slab B: 118560 px * 288ch max = 68.3MB

  hipMemsetAsync(d_ws, 0, 49152, stream);  // stats sums

  auto halo_grid = [](int CS) { return (4 * 968 * (CS / 8) + 255) / 256; };

  k_halo<<<halo_grid(256), 256, 0, stream>>>(SLA, 256);
  k_pack_x<<<P_TOT / 16, 512, 0, stream>>>(x, SLA);
  k_pack_w<<<(663552 + 255) / 256, 256, 0, stream>>>(w1r, w1i, A1, 0, 288, 256, 144, 256, 663552);
  k_pack_w<<<(497664 + 255) / 256, 256, 0, stream>>>(w2r, w2i, A2, 1, 192, 288, 96, 144, 497664);
  k_pack_w<<<(331776 + 255) / 256, 256, 0, stream>>>(w3r, w3i, A3, 1, 192, 192, 96, 96, 331776);
  k_pack_w<<<(331776 + 255) / 256, 256, 0, stream>>>(w4r, w4i, A4, 1, 192, 192, 96, 96, 331776);
  k_pack_w<<<(13824 + 255) / 256, 256, 0, stream>>>(wc, wg, AH, 2, 16, 96, 0, 96, 13824);
  k_halo<<<halo_grid(288), 256, 0, stream>>>(SLB, 288);

  // L1: 256 -> 288  (read SLA/256, write SLB/288)
  k_gemm<96, 288, 256, 2, 2, false><<<1536, 256, 0, stream>>>(SLA, A1, SLB, nullptr, nullptr, nullptr, S(0), Q(0));
  k_packip<288><<<P_TOT * 9 / 256, 256, 0, stream>>>(SLB, S(0), Q(0), g1, b1);
  k_halo<<<halo_grid(192), 256, 0, stream>>>(SLA, 192);

  // L2: 288 -> 192  (read SLB/288, write SLA/192)
  k_gemm<96, 192, 288, 2, 2, false><<<1024, 256, 0, stream>>>(SLB, A2, SLA, nullptr, nullptr, nullptr, S(1), Q(1));
  k_packip<192><<<P_TOT * 6 / 256, 256, 0, stream>>>(SLA, S(1), Q(1), g2, b2);
  k_halo<<<halo_grid(192), 256, 0, stream>>>(SLB, 192);

  // L3: 192 -> 192  (read SLA/192, write SLB/192)
  k_gemm<96, 192, 192, 2, 2, false><<<1024, 256, 0, stream>>>(SLA, A3, SLB, nullptr, nullptr, nullptr, S(2), Q(2));
  k_packip<192><<<P_TOT * 6 / 256, 256, 0, stream>>>(SLB, S(2), Q(2), g3, b3);

  // L4: 192 -> 192  (read SLB/192, write SLA/192; SLA halo already zeroed at 192 geom)
  k_gemm<96, 192, 192, 2, 2, false><<<1024, 256, 0, stream>>>(SLB, A4, SLA, nullptr, nullptr, nullptr, S(3), Q(3));
  k_halo<<<halo_grid(96), 256, 0, stream>>>(SLB, 96);

  // BN+ReLU+magnitude -> 96ch head input (read SLA/192, write SLB/96)
  k_mag<<<P_TOT * 12 / 256, 256, 0, stream>>>(SLA, S(3), Q(3), g4, b4, SLB);

  // head: 96 -> 3 (sigmoid on ch0), writes NCHW fp32 output
  k_gemm<16, 16, 96, 1, 2, true><<<512, 128, 0, stream>>>(SLB, AH, nullptr, out, bcp, bgp, nullptr, nullptr);

  (void)in_sizes; (void)n_in; (void)out_size;
}